// Round 1
// baseline (229.334 us; speedup 1.0000x reference)
//
#include <hip/hip_runtime.h>
#include <hip/hip_bf16.h>

#define HS 4096
#define NE 64
constexpr int CHUNK = 128;   // k-dims staged per LDS chunk
constexpr int T     = 8;     // tokens per wave
constexpr int WAVES = 4;     // waves per block (256 threads)

// Kernel 1: partial logits. Grid (n_tokens/(WAVES*T), ksplit), block 256.
// lane = expert; W chunk staged in LDS swizzled; x read via wave-uniform loads.
__global__ __launch_bounds__(256, 2)
void router_partial(const float* __restrict__ x, const float* __restrict__ W,
                    float* __restrict__ ws, int n_tokens, int k_per_split)
{
    __shared__ float w_lds[NE * CHUNK];   // 32 KiB, stored as swizzled float4 slots

    const int tid  = threadIdx.x;
    const int lane = tid & 63;
    // readfirstlane -> SGPR so token addressing is provably wave-uniform (s_load path)
    const int wid  = __builtin_amdgcn_readfirstlane(tid >> 6);
    const int k0   = blockIdx.y * k_per_split;
    const int token0 = blockIdx.x * (WAVES * T) + wid * T;

    float acc[T];
    #pragma unroll
    for (int t = 0; t < T; ++t) acc[t] = 0.f;

    // staging decomposition: 256 threads cover 8 expert rows x 32 float4 groups
    const int h4 = tid & 31;   // 16B group within a 128-dword row
    const int e0 = tid >> 5;   // 0..7

    for (int hc = 0; hc < k_per_split; hc += CHUNK) {
        __syncthreads();
        // stage W[e][k0+hc .. +CHUNK) into LDS, swizzled: slot = e*32 + (h4 ^ (e&7))
        #pragma unroll
        for (int ee = 0; ee < NE; ee += 8) {
            int e = e0 + ee;
            float4 v = *reinterpret_cast<const float4*>(&W[(size_t)e * HS + k0 + hc + h4 * 4]);
            reinterpret_cast<float4*>(w_lds)[e * (CHUNK / 4) + (h4 ^ (e & 7))] = v;
        }
        __syncthreads();

        for (int sub = 0; sub < CHUNK; sub += 32) {
            // 32 W values for this lane's expert into registers (8x ds_read_b128)
            float w_reg[32];
            #pragma unroll
            for (int g = 0; g < 8; ++g) {
                float4 v = reinterpret_cast<const float4*>(w_lds)
                               [lane * (CHUNK / 4) + (((sub >> 2) + g) ^ (lane & 7))];
                w_reg[g * 4 + 0] = v.x; w_reg[g * 4 + 1] = v.y;
                w_reg[g * 4 + 2] = v.z; w_reg[g * 4 + 3] = v.w;
            }
            #pragma unroll
            for (int t = 0; t < T; ++t) {
                const float* __restrict__ xp =
                    x + (size_t)(token0 + t) * HS + k0 + hc + sub;   // wave-uniform
                #pragma unroll
                for (int j = 0; j < 32; ++j)
                    acc[t] = fmaf(xp[j], w_reg[j], acc[t]);
            }
        }
    }

    #pragma unroll
    for (int t = 0; t < T; ++t)
        ws[((size_t)blockIdx.y * n_tokens + token0 + t) * NE + lane] = acc[t];
}

// Kernel 2: reduce k-splits + softmax + top-2. One wave per token, lane = expert.
__global__ __launch_bounds__(256)
void router_finish(const float* __restrict__ ws, float* __restrict__ out,
                   int n_tokens, int ksplit)
{
    const int lane  = threadIdx.x & 63;
    const int token = blockIdx.x * 4 + (threadIdx.x >> 6);
    if (token >= n_tokens) return;

    float v = ws[(size_t)token * NE + lane];
    if (ksplit == 2) v += ws[(size_t)n_tokens * NE + (size_t)token * NE + lane];

    // max over 64 lanes
    float m1 = v;
    #pragma unroll
    for (int off = 32; off >= 1; off >>= 1) m1 = fmaxf(m1, __shfl_xor(m1, off));
    // lowest-index argmax (matches lax.top_k tie-breaking)
    unsigned long long b1 = __ballot(v == m1);
    int i1 = __ffsll(b1) - 1;

    const float NINF = __int_as_float(0xff800000);
    float vx = (lane == i1) ? NINF : v;
    float m2 = vx;
    #pragma unroll
    for (int off = 32; off >= 1; off >>= 1) m2 = fmaxf(m2, __shfl_xor(m2, off));
    unsigned long long b2 = __ballot(vx == m2);
    int i2 = __ffsll(b2) - 1;

    // softmax denominator
    float s = __expf(v - m1);
    #pragma unroll
    for (int off = 32; off >= 1; off >>= 1) s += __shfl_xor(s, off);

    if (lane == 0) {
        float inv = 1.0f / s;                       // exp(m1-m1)/s
        out[(size_t)token * 2 + 0] = inv;
        out[(size_t)token * 2 + 1] = __expf(m2 - m1) * inv;
        // indices chunk: harness reads whole d_out as float32 -> write as floats
        out[(size_t)n_tokens * 2 + (size_t)token * 2 + 0] = (float)i1;
        out[(size_t)n_tokens * 2 + (size_t)token * 2 + 1] = (float)i2;
    }
}

extern "C" void kernel_launch(void* const* d_in, const int* in_sizes, int n_in,
                              void* d_out, int out_size, void* d_ws, size_t ws_size,
                              hipStream_t stream)
{
    const float* x = (const float*)d_in[0];
    const float* W = (const float*)d_in[1];
    float* out = (float*)d_out;
    float* ws  = (float*)d_ws;

    const int n_tokens = in_sizes[0] / HS;   // 8192
    // K-split=2 doubles block count (occupancy) at the cost of 4 MiB workspace
    const size_t need2 = (size_t)2 * n_tokens * NE * sizeof(float);
    const int ksplit = (ws_size >= need2) ? 2 : 1;
    const int kps = HS / ksplit;

    dim3 grid1(n_tokens / (WAVES * T), ksplit);
    router_partial<<<grid1, 256, 0, stream>>>(x, W, ws, n_tokens, kps);

    dim3 grid2((n_tokens + 3) / 4);
    router_finish<<<grid2, 256, 0, stream>>>(ws, out, n_tokens, ksplit);
}

// Round 2
// 172.798 us; speedup vs baseline: 1.3272x; 1.3272x over previous
//
#include <hip/hip_runtime.h>
#include <hip/hip_bf16.h>

#define HS 4096
#define NE 64
constexpr int KC  = 512;        // k-slice staged in LDS: 64 rows x 512 f32 = 128 KiB
constexpr int T   = 16;         // tokens per wave
constexpr int NW  = 16;         // waves per block (1024 threads)
constexpr int TPB = NW * T;     // 256 tokens per block

// Kernel 1: partial logits. Grid (n_tokens/TPB, ksplit), block 1024.
// lane = expert. Whole W k-slice staged ONCE (XOR-swizzled), then a
// barrier-free inner loop: ds_read_b128 (W) + scalar-loaded x + v_fmac.
__global__ __launch_bounds__(1024, 4)
void router_partial(const float* __restrict__ x, const float* __restrict__ W,
                    float* __restrict__ ws, int n_tokens, int k_per_split)
{
    __shared__ float w_lds[NE * KC];                 // 128 KiB
    float4* w4 = reinterpret_cast<float4*>(w_lds);

    const int tid  = threadIdx.x;
    const int lane = tid & 63;
    const int wid  = __builtin_amdgcn_readfirstlane(tid >> 6);
    const int k0   = blockIdx.y * k_per_split;
    const int token0 = blockIdx.x * TPB + wid * T;
    const int swz  = lane & 31;                      // 5-bit XOR swizzle key

    float acc[T];
    #pragma unroll
    for (int t = 0; t < T; ++t) acc[t] = 0.f;

    // staging decomposition: 1024 threads = 64 rows x 16 float4 slots, 8 rounds
    const int se = tid >> 4;      // expert row 0..63
    const int sh = tid & 15;      // float4 slot within round

    for (int kc = 0; kc < k_per_split; kc += KC) {   // 1 iter on the ksplit=8 path
        if (kc) __syncthreads();
        #pragma unroll
        for (int r = 0; r < KC / 4 / 16; ++r) {      // 8 rounds x 16 KB
            int slot = r * 16 + sh;                  // 0..127
            float4 v = *reinterpret_cast<const float4*>(
                &W[(size_t)se * HS + k0 + kc + slot * 4]);
            w4[se * (KC / 4) + (slot ^ (se & 31))] = v;   // swizzled write
        }
        __syncthreads();

        #pragma unroll 1                              // keep body I$-resident
        for (int sub = 0; sub < KC; sub += 32) {
            const int c = sub >> 2;                   // base float4 slot
            float w_reg[32];
            #pragma unroll
            for (int g = 0; g < 8; ++g) {             // 8x ds_read_b128, swizzled
                float4 v = w4[lane * (KC / 4) + ((c + g) ^ swz)];
                w_reg[g*4+0] = v.x; w_reg[g*4+1] = v.y;
                w_reg[g*4+2] = v.z; w_reg[g*4+3] = v.w;
            }
            #pragma unroll
            for (int t = 0; t < T; ++t) {
                const float* __restrict__ xp =        // wave-uniform -> s_load
                    x + (size_t)(token0 + t) * HS + k0 + kc + sub;
                #pragma unroll
                for (int j = 0; j < 32; ++j)
                    acc[t] = fmaf(xp[j], w_reg[j], acc[t]);
            }
        }
    }

    #pragma unroll
    for (int t = 0; t < T; ++t)
        ws[((size_t)blockIdx.y * n_tokens + token0 + t) * NE + lane] = acc[t];
}

// Kernel 2: reduce k-splits + softmax + top-2. One wave per token, lane = expert.
__global__ __launch_bounds__(256)
void router_finish(const float* __restrict__ ws, float* __restrict__ out,
                   int n_tokens, int ksplit)
{
    const int lane  = threadIdx.x & 63;
    const int token = blockIdx.x * 4 + (threadIdx.x >> 6);
    if (token >= n_tokens) return;

    float v = 0.f;
    for (int s = 0; s < ksplit; ++s)
        v += ws[(size_t)s * n_tokens * NE + (size_t)token * NE + lane];

    // max over 64 lanes
    float m1 = v;
    #pragma unroll
    for (int off = 32; off >= 1; off >>= 1) m1 = fmaxf(m1, __shfl_xor(m1, off));
    // lowest-index argmax (matches lax.top_k tie-breaking)
    unsigned long long b1 = __ballot(v == m1);
    int i1 = __ffsll(b1) - 1;

    const float NINF = __int_as_float(0xff800000);
    float vx = (lane == i1) ? NINF : v;
    float m2 = vx;
    #pragma unroll
    for (int off = 32; off >= 1; off >>= 1) m2 = fmaxf(m2, __shfl_xor(m2, off));
    unsigned long long b2 = __ballot(vx == m2);
    int i2 = __ffsll(b2) - 1;

    // softmax denominator
    float s = __expf(v - m1);
    #pragma unroll
    for (int off = 32; off >= 1; off >>= 1) s += __shfl_xor(s, off);

    if (lane == 0) {
        float inv = 1.0f / s;                         // exp(m1-m1)/s
        out[(size_t)token * 2 + 0] = inv;
        out[(size_t)token * 2 + 1] = __expf(m2 - m1) * inv;
        // indices chunk: harness reads d_out as flat float32 -> write as floats
        out[(size_t)n_tokens * 2 + (size_t)token * 2 + 0] = (float)i1;
        out[(size_t)n_tokens * 2 + (size_t)token * 2 + 1] = (float)i2;
    }
}

extern "C" void kernel_launch(void* const* d_in, const int* in_sizes, int n_in,
                              void* d_out, int out_size, void* d_ws, size_t ws_size,
                              hipStream_t stream)
{
    const float* x = (const float*)d_in[0];
    const float* W = (const float*)d_in[1];
    float* out = (float*)d_out;
    float* ws  = (float*)d_ws;

    const int n_tokens = in_sizes[0] / HS;            // 8192
    int ksplit = 8;                                   // 16 MiB partials
    while (ksplit > 1 &&
           (size_t)ksplit * n_tokens * NE * sizeof(float) > ws_size)
        ksplit >>= 1;
    const int kps = HS / ksplit;

    dim3 grid1(n_tokens / TPB, ksplit);               // (32, 8) = 256 blocks
    router_partial<<<grid1, 1024, 0, stream>>>(x, W, ws, n_tokens, kps);

    dim3 grid2((n_tokens + 3) / 4);
    router_finish<<<grid2, 256, 0, stream>>>(ws, out, n_tokens, ksplit);
}